// Round 15
// baseline (749.372 us; speedup 1.0000x reference)
//
#include <hip/hip_runtime.h>
#include <hip/hip_fp8.h>

#define PTS 8192          // B*N = 4*2048 points
#define HDIM 512
#define BN_EPS 1e-4f
#define HSTRB 528         // LDS row stride in BYTES (fp8 cols)
#define TS 256.0f         // tangent-stream scale (keeps JVP streams out of e4m3 subnormals)

typedef unsigned short u16;
typedef unsigned char u8;
typedef long long i64;
typedef u16 u16x8 __attribute__((ext_vector_type(8)));
typedef short s16x8 __attribute__((ext_vector_type(8)));
typedef float f32x4 __attribute__((ext_vector_type(4)));
typedef float f32x2 __attribute__((ext_vector_type(2)));

__device__ __forceinline__ float bf2f(u16 u) {
  unsigned x = ((unsigned)u) << 16;
  return __builtin_bit_cast(float, x);
}
__device__ __forceinline__ u16 f2bf(float f) {
  unsigned x = __builtin_bit_cast(unsigned, f);
  x += 0x7fffu + ((x >> 16) & 1u);
  return (u16)(x >> 16);
}
// native HW fp8 convert (v_cvt_pk_fp8_f32; OCP e4m3 on gfx950)
__device__ __forceinline__ u8 f2f8(float x) {
  int v = __builtin_amdgcn_cvt_pk_fp8_f32(x, x, 0, false);
  return (u8)(v & 0xff);
}
__device__ __forceinline__ unsigned pk4_f8(float a, float b, float c, float d) {
  int v = __builtin_amdgcn_cvt_pk_fp8_f32(a, b, 0, false);
  v = __builtin_amdgcn_cvt_pk_fp8_f32(c, d, v, true);
  return (unsigned)v;
}
__device__ __forceinline__ float sigf(float x) {
  return __builtin_amdgcn_rcpf(1.f + __expf(-x));
}
__device__ __forceinline__ float fast_tanh(float x) {
  float e = __expf(2.f * x);
  return 1.f - 2.f * __builtin_amdgcn_rcpf(e + 1.f);
}
__device__ __forceinline__ void gl2lds16(const u16* g, u16* l) {
  __builtin_amdgcn_global_load_lds(
      (const __attribute__((address_space(1))) void*)g,
      (__attribute__((address_space(3))) void*)l, 16, 0, 0);
}

// ---------------------------------------------------------------- prep
struct PrepArgs {
  const float *W1, *W2;
  u8 *W1s, *W2s;       // fp8 e4m3, frag-order: [16 chunks][8 waves][4 j][64 lanes][8 B]
  const float* c;
  u16* cb;
  const float *Wg0, *Wg1, *Wg2, *Wb0, *Wb1, *Wb2;
  const float *bg0, *bg1, *bg2;
  u16* Wpack;          // [6*512][64] bf16
  float* bias_pack;    // [3072]
  const float *x, *m1, *v1, *lg1, *be1;
  float *x_cur, *lp_state;
  const float *Wg3, *bg3, *Wb3;
  float *G3, *B3;
  const float *W0, *b0, *b1, *b2, *W3;
  float *E0, *E1, *E2;   // packed epilogue params
};
__global__ void prep_kernel(PrepArgs a) {
  int i = blockIdx.x * 256 + threadIdx.x;   // 0 .. 524287
  if (i < 512 * 512) {
    int n = i >> 9, k = i & 511;
    int c = k >> 5, kin = k & 31, q = kin >> 3, b = kin & 7;
    int w = n >> 6, nin = n & 63, j = nin >> 4, lr = nin & 15;
    size_t d = ((((size_t)(c * 8 + w) * 4 + j) * 64) + (q * 16 + lr)) * 8 + b;
    a.W1s[d] = f2f8(a.W1[i]);
    a.W2s[d] = f2f8(a.W2[i]);
  }
  if (i < PTS * 64) a.cb[i] = f2bf(a.c[i]);
  if (i < 6 * 512 * 64) {
    int sec = i >> 15;
    int within = i & 32767;
    int o = within >> 6, k = within & 63;
    const float* src[6] = {a.Wg0, a.Wg1, a.Wg2, a.Wb0, a.Wb1, a.Wb2};
    a.Wpack[i] = f2bf(src[sec][o * 65 + 1 + k]);
  }
  if (i < 3072) {
    int sec = i >> 9, o = i & 511;
    const float* bgl[3] = {a.bg0, a.bg1, a.bg2};
    a.bias_pack[i] = (sec < 3) ? bgl[sec][o] : 0.f;
  }
  if (i < 512) {
    int o = i;
    a.E0[o * 8 + 0] = a.W0[o * 3];
    a.E0[o * 8 + 1] = a.W0[o * 3 + 1];
    a.E0[o * 8 + 2] = a.W0[o * 3 + 2];
    a.E0[o * 8 + 3] = a.b0[o];
    a.E0[o * 8 + 4] = a.Wg0[o * 65];
    a.E0[o * 8 + 5] = a.Wb0[o * 65];
    a.E0[o * 8 + 6] = 0.f; a.E0[o * 8 + 7] = 0.f;
    a.E1[o * 4 + 0] = a.b1[o];
    a.E1[o * 4 + 1] = a.Wg1[o * 65];
    a.E1[o * 4 + 2] = a.Wb1[o * 65];
    a.E1[o * 4 + 3] = 0.f;
    a.E2[o * 8 + 0] = a.b2[o];
    a.E2[o * 8 + 1] = a.Wg2[o * 65];
    a.E2[o * 8 + 2] = a.Wb2[o * 65];
    a.E2[o * 8 + 3] = a.W3[o];
    a.E2[o * 8 + 4] = a.W3[512 + o];
    a.E2[o * 8 + 5] = a.W3[1024 + o];
    a.E2[o * 8 + 6] = 0.f; a.E2[o * 8 + 7] = 0.f;
  }
  if (i < PTS * 3) {
    int d = i % 3;
    a.x_cur[i] = (a.x[i] - a.m1[d]) * __expf(a.lg1[d]) * rsqrtf(a.v1[d] + BN_EPS) + a.be1[d];
  }
  if (i < PTS) a.lp_state[i] = 0.f;
  {
    int lane = threadIdx.x & 63;
    int p = (blockIdx.x * 256 + threadIdx.x) >> 6;   // 0..8191
    float cv = a.c[(size_t)p * 64 + lane];
    float ag[3], ab[3];
    #pragma unroll
    for (int o = 0; o < 3; ++o) {
      ag[o] = cv * a.Wg3[o * 65 + 1 + lane];
      ab[o] = cv * a.Wb3[o * 65 + 1 + lane];
    }
    #pragma unroll
    for (int off = 32; off > 0; off >>= 1) {
      #pragma unroll
      for (int o = 0; o < 3; ++o) {
        ag[o] += __shfl_xor(ag[o], off);
        ab[o] += __shfl_xor(ab[o], off);
      }
    }
    if (lane == 0) {
      #pragma unroll
      for (int o = 0; o < 3; ++o) {
        a.G3[p * 3 + o] = ag[o] + a.bg3[o];
        a.B3[p * 3 + o] = ab[o];
      }
    }
  }
}

// ---------------------------------------------------------------- gates GEMM (bf16, proven)
struct GatesGemmArgs {
  const u16 *A, *W;
  const float* bias;
  u16* GBi;                // [3][8192][1024] interleaved
};
__global__ __launch_bounds__(256) void gates_gemm(GatesGemmArgs a) {
  __shared__ u16 As[128 * 32];
  __shared__ u16 Bs[128 * 32];
  int tid = threadIdx.x;
  int m0 = blockIdx.x * 128, n0 = blockIdx.y * 128;
  int wave = tid >> 6, lane = tid & 63;
  int wm = (wave & 1) * 64, wn = (wave >> 1) * 64;
  int lr = lane & 15, quad = lane >> 4;

  int rowS = tid >> 2, colS = (tid & 3) * 8;
  const u16* gA0 = a.A + (size_t)(m0 + rowS) * 64 + colS;
  const u16* gB0 = a.W + (size_t)(n0 + rowS) * 64 + colS;
  u16* sA0 = &As[tid * 8];
  u16* sA1 = &As[2048 + tid * 8];
  u16* sB0 = &Bs[tid * 8];
  u16* sB1 = &Bs[2048 + tid * 8];

  f32x4 acc[4][4];
  #pragma unroll
  for (int i = 0; i < 4; ++i)
    #pragma unroll
    for (int j = 0; j < 4; ++j)
      #pragma unroll
      for (int r = 0; r < 4; ++r) acc[i][j][r] = 0.f;

  for (int k0 = 0; k0 < 64; k0 += 32) {
    if (k0) __syncthreads();
    gl2lds16(gA0 + k0, sA0);
    gl2lds16(gA0 + (size_t)64 * 64 + k0, sA1);
    gl2lds16(gB0 + k0, sB0);
    gl2lds16(gB0 + (size_t)64 * 64 + k0, sB1);
    __syncthreads();
    s16x8 af[4], bfr[4];
    #pragma unroll
    for (int i = 0; i < 4; ++i)
      af[i] = *(const s16x8*)&As[(wm + i * 16 + lr) * 32 + quad * 8];
    #pragma unroll
    for (int j = 0; j < 4; ++j)
      bfr[j] = *(const s16x8*)&Bs[(wn + j * 16 + lr) * 32 + quad * 8];
    #pragma unroll
    for (int i = 0; i < 4; ++i)
      #pragma unroll
      for (int j = 0; j < 4; ++j)
        acc[i][j] = __builtin_amdgcn_mfma_f32_16x16x32_bf16(af[i], bfr[j], acc[i][j], 0, 0, 0);
  }

  #pragma unroll
  for (int j = 0; j < 4; ++j) {
    int n = n0 + wn + j * 16 + lr;
    int sec = n >> 9, col = n & 511;
    int l = (sec < 3) ? sec : sec - 3;
    int off = col * 2 + ((sec < 3) ? 0 : 1);
    float bv = a.bias[n];
    u16* outp = a.GBi + (size_t)l * PTS * 1024 + off;
    #pragma unroll
    for (int i = 0; i < 4; ++i) {
      int mrow = m0 + wm + i * 16 + quad * 4;
      #pragma unroll
      for (int r = 0; r < 4; ++r)
        outp[(size_t)(mrow + r) * 1024] = f2bf(acc[i][j][r] + bv);
    }
  }
}

// ---------------------------------------------------------------- persistent flow kernel
// 512 blocks x 512 threads (8 waves); block owns 16 points for ALL 12 stages.
// No cross-block communication: accum6/x/kx/kl/lp live in LDS. Round-14 stage
// body verbatim (proven 64-VGPR no-spill); stage loop is #pragma unroll 1.
struct FlowArgs {
  const float* sqrtT;
  const float *G3, *B3, *Wg3, *Wb3, *b3;
  const float* x0;
  float* lp_state;
  const u16 *GBi0, *GBi1, *GBi2;   // interleaved gate tables [PTS][1024]
  const float *E0, *E1, *E2;       // packed params
  const u8 *W1s, *W2s;             // fp8 weights frag-order [16][8][4][64][8]
  const float *m2, *v2, *lg2, *be2;
  float* out_x;
};

__global__ __launch_bounds__(512, 4) void flow_kernel(FlowArgs a) {
  __shared__ __align__(16) u8 Hs[64 * HSTRB];     // 33.8 KB (fp8 activations)
  __shared__ float xe[16][3];
  __shared__ float part[8][16][6];
  __shared__ float xb[16][3], kxs[16][3], kls[16], lps[16], ac6[16][6];
  __shared__ float g3l[16][3], b3l[16][3];
  int tid = threadIdx.x;
  int w = tid >> 6, lane = tid & 63, lr = lane & 15, quad = lane >> 4;
  int n0 = w * 64;
  int p0 = blockIdx.x * 16;
  float s0 = a.sqrtT[0];
  float dt = s0 * s0 * (1.f / 3.f);

  // wave-local W slice base pointers (frag-order)
  const u8* w1l = a.W1s + (size_t)w * 2048 + (size_t)lane * 8;
  const u8* w2l = a.W2s + (size_t)w * 2048 + (size_t)lane * 8;

  int pl0 = tid >> 5;
  int base_o = (tid & 31) * 16;
  const u16* g0row = a.GBi0 + (size_t)(p0 + pl0) * 1024 + 2 * base_o;

  // ---- init block-local state
  if (tid < 16) {
    int p = p0 + tid;
    xb[tid][0] = a.x0[p * 3]; xb[tid][1] = a.x0[p * 3 + 1]; xb[tid][2] = a.x0[p * 3 + 2];
    lps[tid] = 0.f;
    #pragma unroll
    for (int r = 0; r < 3; ++r) {
      g3l[tid][r] = a.G3[p * 3 + r];
      b3l[tid][r] = a.B3[p * 3 + r];
    }
  }
  __syncthreads();

  #pragma unroll 1
  for (int s = 0; s < 12; ++s) {
    int sm = s & 3;
    float ts = (float)(s >> 2) + (sm == 0 ? 0.f : (sm == 3 ? 1.f : 0.5f));
    float t = ts * dt;

    // ---- preload W1 chunk 0 into registers (L2 latency overlaps fold + L0)
    i64 bc[4], bn[4];
    #pragma unroll
    for (int j = 0; j < 4; ++j) bc[j] = *(const i64*)(w1l + (size_t)j * 512);

    // ---- issue L0 gate loads EARLY (independent of fold)
    u16x8 gc0 = *(const u16x8*)(g0row);
    u16x8 gc1 = *(const u16x8*)(g0row + 8);
    u16x8 gc2 = *(const u16x8*)(g0row + 16);
    u16x8 gc3 = *(const u16x8*)(g0row + 24);

    // ---- fold previous stage (thread per point)
    if (tid < 16) {
      float o0 = xb[tid][0], o1 = xb[tid][1], o2 = xb[tid][2];
      if (s > 0) {
        int pm = (s - 1) & 3;
        float tsp = (float)((s - 1) >> 2) + (pm == 0 ? 0.f : (pm == 3 ? 1.f : 0.5f));
        float tp = tsp * dt;
        float dx[3], gate[3];
        #pragma unroll
        for (int r = 0; r < 3; ++r) {
          gate[r] = sigf(g3l[tid][r] + tp * a.Wg3[r * 65]);
          float bias = b3l[tid][r] + tp * a.Wb3[r * 65];
          dx[r] = fmaf(ac6[tid][r] + a.b3[r], gate[r], bias);
        }
        float klv = -(ac6[tid][3] * gate[0] + ac6[tid][4] * gate[1] + ac6[tid][5] * gate[2]);
        if (pm == 0) {
          #pragma unroll
          for (int r = 0; r < 3; ++r) {
            kxs[tid][r] = dx[r];
            (&o0)[r] = xb[tid][r] + 0.5f * dt * dx[r];
          }
          kls[tid] = klv;
        } else if (pm == 1) {
          #pragma unroll
          for (int r = 0; r < 3; ++r) {
            kxs[tid][r] += 2.f * dx[r];
            (&o0)[r] = xb[tid][r] + 0.5f * dt * dx[r];
          }
          kls[tid] += 2.f * klv;
        } else if (pm == 2) {
          #pragma unroll
          for (int r = 0; r < 3; ++r) {
            kxs[tid][r] += 2.f * dx[r];
            (&o0)[r] = xb[tid][r] + dt * dx[r];
          }
          kls[tid] += 2.f * klv;
        } else {
          float sc = dt * (1.f / 6.f);
          #pragma unroll
          for (int r = 0; r < 3; ++r) {
            xb[tid][r] += sc * (kxs[tid][r] + dx[r]);
            (&o0)[r] = xb[tid][r];
          }
          lps[tid] += sc * (kls[tid] + klv);
        }
      }
      xe[tid][0] = o0; xe[tid][1] = o1; xe[tid][2] = o2;
    }
    __syncthreads();

    // ---- layer0: 32 threads per point, 16 cols each -> H1 (fp8) in LDS
    {
      float x0v = xe[pl0][0], x1v = xe[pl0][1], x2v = xe[pl0][2];
      u16x8 gcv[4] = {gc0, gc1, gc2, gc3};
      #pragma unroll
      for (int cc = 0; cc < 4; ++cc) {
        u16x8 v = gcv[cc];
        float hk[4], d0k[4], d1k[4], d2k[4];
        #pragma unroll
        for (int k = 0; k < 4; ++k) {
          int o = base_o + cc * 4 + k;
          f32x4 e = *(const f32x4*)(a.E0 + (size_t)o * 8);
          f32x2 e2 = *(const f32x2*)(a.E0 + (size_t)o * 8 + 4);
          float u = fmaf(e[0], x0v, fmaf(e[1], x1v, e[2] * x2v)) + e[3];
          float gate = sigf(bf2f(v[2 * k]) + t * e2[0]);
          float bias = bf2f(v[2 * k + 1]) + t * e2[1];
          float z = fmaf(u, gate, bias);
          float h = fast_tanh(z);
          float wm = (1.f - h * h) * gate * TS;
          hk[k] = h;
          d0k[k] = wm * e[0];
          d1k[k] = wm * e[1];
          d2k[k] = wm * e[2];
        }
        size_t hb = (size_t)(pl0 * 4) * HSTRB + base_o + cc * 4;
        *(unsigned*)(Hs + hb) = pk4_f8(hk[0], hk[1], hk[2], hk[3]);
        *(unsigned*)(Hs + hb + HSTRB) = pk4_f8(d0k[0], d0k[1], d0k[2], d0k[3]);
        *(unsigned*)(Hs + hb + 2 * HSTRB) = pk4_f8(d1k[0], d1k[1], d1k[2], d1k[3]);
        *(unsigned*)(Hs + hb + 3 * HSTRB) = pk4_f8(d2k[0], d2k[1], d2k[2], d2k[3]);
      }
    }

    // ---- prefetch epilogue-1 gate dwords (hidden behind GEMM1)
    unsigned g1v[4][4];
    #pragma unroll
    for (int j = 0; j < 4; ++j)
      #pragma unroll
      for (int i = 0; i < 4; ++i) {
        int n = n0 + j * 16 + lr;
        int p = p0 + i * 4 + quad;
        g1v[j][i] = *(const unsigned*)(a.GBi1 + (size_t)p * 1024 + 2 * n);
      }
    __syncthreads();   // H1 visible to all waves

    // ---- layer1 GEMM: register-pipelined W, NO barriers
    f32x4 acc[4][4];
    #pragma unroll
    for (int i = 0; i < 4; ++i)
      #pragma unroll
      for (int j = 0; j < 4; ++j)
        #pragma unroll
        for (int r = 0; r < 4; ++r) acc[i][j][r] = 0.f;
    {
      #pragma unroll 1
      for (int c = 0; c < 16; ++c) {
        const u8* nsrc = (c < 15) ? (w1l + (size_t)(c + 1) * 16384) : w2l;
        #pragma unroll
        for (int j = 0; j < 4; ++j) bn[j] = *(const i64*)(nsrc + (size_t)j * 512);
        int k0 = c * 32;
        i64 af[4];
        #pragma unroll
        for (int i = 0; i < 4; ++i)
          af[i] = *(const i64*)(Hs + (size_t)(i * 16 + lr) * HSTRB + k0 + quad * 8);
        #pragma unroll
        for (int i = 0; i < 4; ++i)
          #pragma unroll
          for (int j = 0; j < 4; ++j)
            acc[i][j] = __builtin_amdgcn_mfma_f32_16x16x32_fp8_fp8(af[i], bc[j], acc[i][j], 0, 0, 0);
        #pragma unroll
        for (int j = 0; j < 4; ++j) bc[j] = bn[j];
      }
    }
    __syncthreads();   // all H1 reads done -> safe to overwrite

    // ---- epilogue1 -> H2 (fp8) in same LDS (FULLY unrolled)
    #pragma unroll
    for (int j = 0; j < 4; ++j) {
      int n = n0 + j * 16 + lr;
      f32x4 e1 = *(const f32x4*)(a.E1 + (size_t)n * 4);
      #pragma unroll
      for (int i = 0; i < 4; ++i) {
        unsigned d = g1v[j][i];
        float gate = sigf(bf2f((u16)(d & 0xffffu)) + t * e1[1]);
        float bias = bf2f((u16)(d >> 16)) + t * e1[2];
        f32x4 u = acc[i][j];
        float z = fmaf(u[0] + e1[0], gate, bias);
        float h = fast_tanh(z);
        float wmf = (1.f - h * h) * gate;
        int row = i * 16 + quad * 4;
        Hs[(size_t)row * HSTRB + n] = f2f8(h);
        Hs[(size_t)(row + 1) * HSTRB + n] = f2f8(u[1] * wmf);
        Hs[(size_t)(row + 2) * HSTRB + n] = f2f8(u[2] * wmf);
        Hs[(size_t)(row + 3) * HSTRB + n] = f2f8(u[3] * wmf);
      }
    }

    // ---- prefetch epilogue-2 gate dwords (hidden behind GEMM2)
    unsigned g2v[4][4];
    #pragma unroll
    for (int j = 0; j < 4; ++j)
      #pragma unroll
      for (int i = 0; i < 4; ++i) {
        int n = n0 + j * 16 + lr;
        int p = p0 + i * 4 + quad;
        g2v[j][i] = *(const unsigned*)(a.GBi2 + (size_t)p * 1024 + 2 * n);
      }
    __syncthreads();   // H2 visible; bc already holds W2 chunk 0

    // ---- layer2 GEMM: register-pipelined W, NO barriers
    #pragma unroll
    for (int i = 0; i < 4; ++i)
      #pragma unroll
      for (int j = 0; j < 4; ++j)
        #pragma unroll
        for (int r = 0; r < 4; ++r) acc[i][j][r] = 0.f;
    {
      #pragma unroll 1
      for (int c = 0; c < 16; ++c) {
        if (c < 15) {
          const u8* nsrc = w2l + (size_t)(c + 1) * 16384;
          #pragma unroll
          for (int j = 0; j < 4; ++j) bn[j] = *(const i64*)(nsrc + (size_t)j * 512);
        }
        int k0 = c * 32;
        i64 af[4];
        #pragma unroll
        for (int i = 0; i < 4; ++i)
          af[i] = *(const i64*)(Hs + (size_t)(i * 16 + lr) * HSTRB + k0 + quad * 8);
        #pragma unroll
        for (int i = 0; i < 4; ++i)
          #pragma unroll
          for (int j = 0; j < 4; ++j)
            acc[i][j] = __builtin_amdgcn_mfma_f32_16x16x32_fp8_fp8(af[i], bc[j], acc[i][j], 0, 0, 0);
        if (c < 15) {
          #pragma unroll
          for (int j = 0; j < 4; ++j) bc[j] = bn[j];
        }
      }
    }

    // ---- epilogue2: gate/tanh + project onto W3 -> 6 partials per point
    #pragma unroll
    for (int i = 0; i < 4; ++i) {
      float v0 = 0.f, v1 = 0.f, v2 = 0.f, v3 = 0.f, v4 = 0.f, v5 = 0.f;
      int pl = i * 4 + quad;
      #pragma unroll
      for (int j = 0; j < 4; ++j) {
        int n = n0 + j * 16 + lr;
        f32x4 ea = *(const f32x4*)(a.E2 + (size_t)n * 8);
        f32x2 eb = *(const f32x2*)(a.E2 + (size_t)n * 8 + 4);
        unsigned d = g2v[j][i];
        float gate = sigf(bf2f((u16)(d & 0xffffu)) + t * ea[1]);
        float bias = bf2f((u16)(d >> 16)) + t * ea[2];
        f32x4 u = acc[i][j];
        float z = fmaf(u[0] + ea[0], gate, bias);
        float h = fast_tanh(z);
        float wmf = (1.f - h * h) * gate;
        float w30 = ea[3], w31 = eb[0], w32 = eb[1];
        v0 = fmaf(h, w30, v0);
        v1 = fmaf(h, w31, v1);
        v2 = fmaf(h, w32, v2);
        v3 = fmaf(u[1] * wmf, w30, v3);
        v4 = fmaf(u[2] * wmf, w31, v4);
        v5 = fmaf(u[3] * wmf, w32, v5);
      }
      #pragma unroll
      for (int mask = 1; mask <= 8; mask <<= 1) {
        v0 += __shfl_xor(v0, mask);
        v1 += __shfl_xor(v1, mask);
        v2 += __shfl_xor(v2, mask);
        v3 += __shfl_xor(v3, mask);
        v4 += __shfl_xor(v4, mask);
        v5 += __shfl_xor(v5, mask);
      }
      // tangent streams carry TS scale through both GEMMs -> undo here
      float val = (lr == 0) ? v0 : (lr == 1) ? v1 : (lr == 2) ? v2
                : (lr == 3) ? v3 * (1.f / TS) : (lr == 4) ? v4 * (1.f / TS)
                : v5 * (1.f / TS);
      if (lr < 6) part[w][pl][lr] = val;
    }
    __syncthreads();

    if (tid < 96) {
      int pt = tid / 6, d = tid - pt * 6;
      float sum = 0.f;
      #pragma unroll
      for (int ww = 0; ww < 8; ++ww) sum += part[ww][pt][d];
      ac6[pt][d] = sum;
    }
    __syncthreads();   // ac6 visible to next stage's fold
  }

  // ---- final fold (mode 3, ts_prev = 3.0) + BN2 + outputs
  if (tid < 16) {
    int p = p0 + tid;
    float tp = 3.f * dt;
    float dx[3], gate[3];
    #pragma unroll
    for (int r = 0; r < 3; ++r) {
      gate[r] = sigf(g3l[tid][r] + tp * a.Wg3[r * 65]);
      float bias = b3l[tid][r] + tp * a.Wb3[r * 65];
      dx[r] = fmaf(ac6[tid][r] + a.b3[r], gate[r], bias);
    }
    float klv = -(ac6[tid][3] * gate[0] + ac6[tid][4] * gate[1] + ac6[tid][5] * gate[2]);
    float sc = dt * (1.f / 6.f);
    #pragma unroll
    for (int r = 0; r < 3; ++r) {
      float xf = xb[tid][r] + sc * (kxs[tid][r] + dx[r]);
      a.out_x[p * 3 + r] = (xf - a.m2[r]) * __expf(a.lg2[r]) * rsqrtf(a.v2[r] + BN_EPS) + a.be2[r];
    }
    a.lp_state[p] = lps[tid] + sc * (kls[tid] + klv);
  }
}

// ---------------------------------------------------------------- finish lp
__global__ void finish_lp(const float* __restrict__ lp_state,
                          const float* __restrict__ v1, const float* __restrict__ lg1,
                          const float* __restrict__ v2, const float* __restrict__ lg2,
                          float* __restrict__ out) {
  int b = blockIdx.x, tid = threadIdx.x;
  float s = 0.f;
  for (int n = tid; n < 2048; n += 256) s += lp_state[b * 2048 + n];
  __shared__ float red[256];
  red[tid] = s;
  __syncthreads();
  for (int w = 128; w > 0; w >>= 1) {
    if (tid < w) red[tid] += red[tid + w];
    __syncthreads();
  }
  if (tid == 0) {
    float ld = 0.f;
    for (int d = 0; d < 3; ++d) {
      ld += lg1[d] - 0.5f * logf(v1[d] + BN_EPS);
      ld += lg2[d] - 0.5f * logf(v2[d] + BN_EPS);
    }
    out[b] = red[0] - 2048.f * ld;
  }
}

// ---------------------------------------------------------------- launch
extern "C" void kernel_launch(void* const* d_in, const int* in_sizes, int n_in,
                              void* d_out, int out_size, void* d_ws, size_t ws_size,
                              hipStream_t stream) {
  const float* x        = (const float*)d_in[0];
  const float* c        = (const float*)d_in[1];
  const float* bn1_mean = (const float*)d_in[2];
  const float* bn1_var  = (const float*)d_in[3];
  const float* bn1_lg   = (const float*)d_in[4];
  const float* bn1_beta = (const float*)d_in[5];
  const float* bn2_mean = (const float*)d_in[6];
  const float* bn2_var  = (const float*)d_in[7];
  const float* bn2_lg   = (const float*)d_in[8];
  const float* bn2_beta = (const float*)d_in[9];
  const float* sqrtT    = (const float*)d_in[10];
  const float* W0  = (const float*)d_in[11];
  const float* b0  = (const float*)d_in[12];
  const float* Wg0 = (const float*)d_in[13];
  const float* bg0 = (const float*)d_in[14];
  const float* Wb0 = (const float*)d_in[15];
  const float* W1  = (const float*)d_in[16];
  const float* b1  = (const float*)d_in[17];
  const float* Wg1 = (const float*)d_in[18];
  const float* bg1 = (const float*)d_in[19];
  const float* Wb1 = (const float*)d_in[20];
  const float* W2  = (const float*)d_in[21];
  const float* b2  = (const float*)d_in[22];
  const float* Wg2 = (const float*)d_in[23];
  const float* bg2 = (const float*)d_in[24];
  const float* Wb2 = (const float*)d_in[25];
  const float* W3  = (const float*)d_in[26];
  const float* b3  = (const float*)d_in[27];
  const float* Wg3 = (const float*)d_in[28];
  const float* bg3 = (const float*)d_in[29];
  const float* Wb3 = (const float*)d_in[30];

  char* base = (char*)d_ws;
  size_t off = 0;
  auto alloc = [&](size_t bytes) -> void* {
    void* pp = base + off;
    off += (bytes + 255) & ~(size_t)255;
    return pp;
  };
  u8* W1s = (u8*)alloc((size_t)512 * 512);
  u8* W2s = (u8*)alloc((size_t)512 * 512);
  u16* cb  = (u16*)alloc((size_t)PTS * 64 * 2);
  u16* Wpack = (u16*)alloc((size_t)6 * 512 * 64 * 2);
  float* bias_pack = (float*)alloc((size_t)3072 * 4);
  u16* GBi = (u16*)alloc((size_t)3 * PTS * 1024 * 2);
  const size_t SZi = (size_t)PTS * 1024;
  u16* GBi0 = GBi;
  u16* GBi1 = GBi + SZi;
  u16* GBi2 = GBi + 2 * SZi;
  float* G3f = (float*)alloc((size_t)PTS * 3 * 4);
  float* B3f = (float*)alloc((size_t)PTS * 3 * 4);
  float* E0 = (float*)alloc((size_t)512 * 8 * 4);
  float* E1 = (float*)alloc((size_t)512 * 4 * 4);
  float* E2 = (float*)alloc((size_t)512 * 8 * 4);
  float* x_cur    = (float*)alloc((size_t)PTS * 3 * 4);
  float* lp_state = (float*)alloc((size_t)PTS * 4);
  (void)ws_size; (void)in_sizes; (void)n_in; (void)out_size;

  PrepArgs pa{W1, W2, W1s, W2s, c, cb, Wg0, Wg1, Wg2, Wb0, Wb1, Wb2,
              bg0, bg1, bg2, Wpack, bias_pack, x, bn1_mean, bn1_var,
              bn1_lg, bn1_beta, x_cur, lp_state, Wg3, bg3, Wb3, G3f, B3f,
              W0, b0, b1, b2, W3, E0, E1, E2};
  prep_kernel<<<2048, 256, 0, stream>>>(pa);

  GatesGemmArgs gg{cb, Wpack, bias_pack, GBi};
  gates_gemm<<<dim3(64, 24), 256, 0, stream>>>(gg);

  FlowArgs fa{sqrtT, G3f, B3f, Wg3, Wb3, b3, x_cur, lp_state,
              GBi0, GBi1, GBi2, E0, E1, E2, W1s, W2s,
              bn2_mean, bn2_var, bn2_lg, bn2_beta, (float*)d_out};
  flow_kernel<<<PTS / 16, 512, 0, stream>>>(fa);

  finish_lp<<<4, 256, 0, stream>>>(lp_state, bn1_var, bn1_lg, bn2_var, bn2_lg,
                                   (float*)d_out + PTS * 3);
}

// Round 16
// 683.988 us; speedup vs baseline: 1.0956x; 1.0956x over previous
//
#include <hip/hip_runtime.h>
#include <hip/hip_fp8.h>

#define PTS 8192          // B*N = 4*2048 points
#define HDIM 512
#define BN_EPS 1e-4f
#define HSTRB 528         // LDS row stride in BYTES (fp8 cols)
#define TS 256.0f         // tangent-stream scale (keeps JVP streams out of e4m3 subnormals)

typedef unsigned short u16;
typedef unsigned char u8;
typedef long long i64;
typedef u16 u16x8 __attribute__((ext_vector_type(8)));
typedef short s16x8 __attribute__((ext_vector_type(8)));
typedef float f32x4 __attribute__((ext_vector_type(4)));
typedef float f32x2 __attribute__((ext_vector_type(2)));

__device__ __forceinline__ float bf2f(u16 u) {
  unsigned x = ((unsigned)u) << 16;
  return __builtin_bit_cast(float, x);
}
__device__ __forceinline__ u16 f2bf(float f) {
  unsigned x = __builtin_bit_cast(unsigned, f);
  x += 0x7fffu + ((x >> 16) & 1u);
  return (u16)(x >> 16);
}
// native HW fp8 convert (v_cvt_pk_fp8_f32; OCP e4m3 on gfx950)
__device__ __forceinline__ u8 f2f8(float x) {
  int v = __builtin_amdgcn_cvt_pk_fp8_f32(x, x, 0, false);
  return (u8)(v & 0xff);
}
__device__ __forceinline__ unsigned pk4_f8(float a, float b, float c, float d) {
  int v = __builtin_amdgcn_cvt_pk_fp8_f32(a, b, 0, false);
  v = __builtin_amdgcn_cvt_pk_fp8_f32(c, d, v, true);
  return (unsigned)v;
}
__device__ __forceinline__ float sigf(float x) {
  return __builtin_amdgcn_rcpf(1.f + __expf(-x));
}
__device__ __forceinline__ float fast_tanh(float x) {
  float e = __expf(2.f * x);
  return 1.f - 2.f * __builtin_amdgcn_rcpf(e + 1.f);
}
__device__ __forceinline__ void gl2lds16(const u16* g, u16* l) {
  __builtin_amdgcn_global_load_lds(
      (const __attribute__((address_space(1))) void*)g,
      (__attribute__((address_space(3))) void*)l, 16, 0, 0);
}

// ---------------------------------------------------------------- prep
struct PrepArgs {
  const float *W1, *W2;
  u8 *W1s, *W2s;       // fp8 e4m3, frag-order: [16 chunks][8 waves][4 j][64 lanes][8 B]
  const float* c;
  u16* cb;
  const float *Wg0, *Wg1, *Wg2, *Wb0, *Wb1, *Wb2;
  const float *bg0, *bg1, *bg2;
  u16* Wpack;          // [6*512][64] bf16
  float* bias_pack;    // [3072]
  const float *x, *m1, *v1, *lg1, *be1;
  float *x_cur, *lp_state;
  const float *Wg3, *bg3, *Wb3;
  float *G3, *B3;
  const float *W0, *b0, *b1, *b2, *W3;
  float *E0, *E1, *E2;   // packed epilogue params
};
__global__ void prep_kernel(PrepArgs a) {
  int i = blockIdx.x * 256 + threadIdx.x;   // 0 .. 524287
  if (i < 512 * 512) {
    int n = i >> 9, k = i & 511;
    int c = k >> 5, kin = k & 31, q = kin >> 3, b = kin & 7;
    int w = n >> 6, nin = n & 63, j = nin >> 4, lr = nin & 15;
    size_t d = ((((size_t)(c * 8 + w) * 4 + j) * 64) + (q * 16 + lr)) * 8 + b;
    a.W1s[d] = f2f8(a.W1[i]);
    a.W2s[d] = f2f8(a.W2[i]);
  }
  if (i < PTS * 64) a.cb[i] = f2bf(a.c[i]);
  if (i < 6 * 512 * 64) {
    int sec = i >> 15;
    int within = i & 32767;
    int o = within >> 6, k = within & 63;
    const float* src[6] = {a.Wg0, a.Wg1, a.Wg2, a.Wb0, a.Wb1, a.Wb2};
    a.Wpack[i] = f2bf(src[sec][o * 65 + 1 + k]);
  }
  if (i < 3072) {
    int sec = i >> 9, o = i & 511;
    const float* bgl[3] = {a.bg0, a.bg1, a.bg2};
    a.bias_pack[i] = (sec < 3) ? bgl[sec][o] : 0.f;
  }
  if (i < 512) {
    int o = i;
    a.E0[o * 8 + 0] = a.W0[o * 3];
    a.E0[o * 8 + 1] = a.W0[o * 3 + 1];
    a.E0[o * 8 + 2] = a.W0[o * 3 + 2];
    a.E0[o * 8 + 3] = a.b0[o];
    a.E0[o * 8 + 4] = a.Wg0[o * 65];
    a.E0[o * 8 + 5] = a.Wb0[o * 65];
    a.E0[o * 8 + 6] = 0.f; a.E0[o * 8 + 7] = 0.f;
    a.E1[o * 4 + 0] = a.b1[o];
    a.E1[o * 4 + 1] = a.Wg1[o * 65];
    a.E1[o * 4 + 2] = a.Wb1[o * 65];
    a.E1[o * 4 + 3] = 0.f;
    a.E2[o * 8 + 0] = a.b2[o];
    a.E2[o * 8 + 1] = a.Wg2[o * 65];
    a.E2[o * 8 + 2] = a.Wb2[o * 65];
    a.E2[o * 8 + 3] = a.W3[o];
    a.E2[o * 8 + 4] = a.W3[512 + o];
    a.E2[o * 8 + 5] = a.W3[1024 + o];
    a.E2[o * 8 + 6] = 0.f; a.E2[o * 8 + 7] = 0.f;
  }
  if (i < PTS * 3) {
    int d = i % 3;
    a.x_cur[i] = (a.x[i] - a.m1[d]) * __expf(a.lg1[d]) * rsqrtf(a.v1[d] + BN_EPS) + a.be1[d];
  }
  if (i < PTS) a.lp_state[i] = 0.f;
  {
    int lane = threadIdx.x & 63;
    int p = (blockIdx.x * 256 + threadIdx.x) >> 6;   // 0..8191
    float cv = a.c[(size_t)p * 64 + lane];
    float ag[3], ab[3];
    #pragma unroll
    for (int o = 0; o < 3; ++o) {
      ag[o] = cv * a.Wg3[o * 65 + 1 + lane];
      ab[o] = cv * a.Wb3[o * 65 + 1 + lane];
    }
    #pragma unroll
    for (int off = 32; off > 0; off >>= 1) {
      #pragma unroll
      for (int o = 0; o < 3; ++o) {
        ag[o] += __shfl_xor(ag[o], off);
        ab[o] += __shfl_xor(ab[o], off);
      }
    }
    if (lane == 0) {
      #pragma unroll
      for (int o = 0; o < 3; ++o) {
        a.G3[p * 3 + o] = ag[o] + a.bg3[o];
        a.B3[p * 3 + o] = ab[o];
      }
    }
  }
}

// ---------------------------------------------------------------- gates GEMM (bf16, proven)
struct GatesGemmArgs {
  const u16 *A, *W;
  const float* bias;
  u16* GBi;                // [3][8192][1024] interleaved
};
__global__ __launch_bounds__(256) void gates_gemm(GatesGemmArgs a) {
  __shared__ u16 As[128 * 32];
  __shared__ u16 Bs[128 * 32];
  int tid = threadIdx.x;
  int m0 = blockIdx.x * 128, n0 = blockIdx.y * 128;
  int wave = tid >> 6, lane = tid & 63;
  int wm = (wave & 1) * 64, wn = (wave >> 1) * 64;
  int lr = lane & 15, quad = lane >> 4;

  int rowS = tid >> 2, colS = (tid & 3) * 8;
  const u16* gA0 = a.A + (size_t)(m0 + rowS) * 64 + colS;
  const u16* gB0 = a.W + (size_t)(n0 + rowS) * 64 + colS;
  u16* sA0 = &As[tid * 8];
  u16* sA1 = &As[2048 + tid * 8];
  u16* sB0 = &Bs[tid * 8];
  u16* sB1 = &Bs[2048 + tid * 8];

  f32x4 acc[4][4];
  #pragma unroll
  for (int i = 0; i < 4; ++i)
    #pragma unroll
    for (int j = 0; j < 4; ++j)
      #pragma unroll
      for (int r = 0; r < 4; ++r) acc[i][j][r] = 0.f;

  for (int k0 = 0; k0 < 64; k0 += 32) {
    if (k0) __syncthreads();
    gl2lds16(gA0 + k0, sA0);
    gl2lds16(gA0 + (size_t)64 * 64 + k0, sA1);
    gl2lds16(gB0 + k0, sB0);
    gl2lds16(gB0 + (size_t)64 * 64 + k0, sB1);
    __syncthreads();
    s16x8 af[4], bfr[4];
    #pragma unroll
    for (int i = 0; i < 4; ++i)
      af[i] = *(const s16x8*)&As[(wm + i * 16 + lr) * 32 + quad * 8];
    #pragma unroll
    for (int j = 0; j < 4; ++j)
      bfr[j] = *(const s16x8*)&Bs[(wn + j * 16 + lr) * 32 + quad * 8];
    #pragma unroll
    for (int i = 0; i < 4; ++i)
      #pragma unroll
      for (int j = 0; j < 4; ++j)
        acc[i][j] = __builtin_amdgcn_mfma_f32_16x16x32_bf16(af[i], bfr[j], acc[i][j], 0, 0, 0);
  }

  #pragma unroll
  for (int j = 0; j < 4; ++j) {
    int n = n0 + wn + j * 16 + lr;
    int sec = n >> 9, col = n & 511;
    int l = (sec < 3) ? sec : sec - 3;
    int off = col * 2 + ((sec < 3) ? 0 : 1);
    float bv = a.bias[n];
    u16* outp = a.GBi + (size_t)l * PTS * 1024 + off;
    #pragma unroll
    for (int i = 0; i < 4; ++i) {
      int mrow = m0 + wm + i * 16 + quad * 4;
      #pragma unroll
      for (int r = 0; r < 4; ++r)
        outp[(size_t)(mrow + r) * 1024] = f2bf(acc[i][j][r] + bv);
    }
  }
}

// ---------------------------------------------------------------- per-stage kernel
// 512 blocks x 512 threads (8 waves); block owns 16 points (64 m-rows).
// W in frag-order; each wave reads ONLY its own 2KB/chunk slice -> W goes straight
// to registers, software-pipelined (coalesced lane*8 loads), ZERO K-loop barriers.
// Register-balanced at 64 VGPR + 64 AGPR = 128/wave (the 4-wave/SIMD cliff).
struct StageArgs {
  const float* sqrtT;
  float ts_prev, ts_cur;
  int mode_prev;             // -1 none, 0,1,2 stage folds, 3 step-end fold
  float* accum6;             // [PTS][6]
  const float *G3, *B3, *Wg3, *Wb3, *b3;
  float *x_cur, *kx, *kl, *lp_state;
  const u16 *GBi0, *GBi1, *GBi2;   // interleaved gate tables [PTS][1024]
  const float *E0, *E1, *E2;       // packed params
  const u8 *W1s, *W2s;             // fp8 weights frag-order [16][8][4][64][8]
};

__global__ __launch_bounds__(512, 4) void stage_kernel(StageArgs a) {
  __shared__ __align__(16) u8 Hs[64 * HSTRB];     // 33.8 KB (fp8 activations)
  __shared__ float xe[16][3];
  __shared__ float part[8][16][6];
  int tid = threadIdx.x;
  int w = tid >> 6, lane = tid & 63, lr = lane & 15, quad = lane >> 4;
  int n0 = w * 64;
  int p0 = blockIdx.x * 16;
  float s0 = a.sqrtT[0];
  float dt = s0 * s0 * (1.f / 3.f);

  // wave-local W slice base pointers (frag-order)
  const u8* w1l = a.W1s + (size_t)w * 2048 + (size_t)lane * 8;
  const u8* w2l = a.W2s + (size_t)w * 2048 + (size_t)lane * 8;

  // ---- preload W1 chunk 0 into registers (L2 latency overlaps fold + L0)
  i64 bc[4], bn[4];
  #pragma unroll
  for (int j = 0; j < 4; ++j) bc[j] = *(const i64*)(w1l + (size_t)j * 512);

  // ---- issue L0 gate loads EARLY (independent of fold)
  int pl0 = tid >> 5;
  int base_o = (tid & 31) * 16;
  const u16* g0row = a.GBi0 + (size_t)(p0 + pl0) * 1024 + 2 * base_o;
  u16x8 gc0 = *(const u16x8*)(g0row);
  u16x8 gc1 = *(const u16x8*)(g0row + 8);
  u16x8 gc2 = *(const u16x8*)(g0row + 16);
  u16x8 gc3 = *(const u16x8*)(g0row + 24);

  // ---- fold previous stage (thread per point)
  if (tid < 16) {
    int p = p0 + tid;
    float xc0 = a.x_cur[p * 3], xc1 = a.x_cur[p * 3 + 1], xc2 = a.x_cur[p * 3 + 2];
    float o0 = xc0, o1 = xc1, o2 = xc2;
    if (a.mode_prev >= 0) {
      float tp = a.ts_prev * dt;
      float dx[3], gate[3];
      #pragma unroll
      for (int r = 0; r < 3; ++r) {
        float fr = a.accum6[(size_t)p * 6 + r];
        gate[r] = sigf(a.G3[p * 3 + r] + tp * a.Wg3[r * 65]);
        float bias = a.B3[p * 3 + r] + tp * a.Wb3[r * 65];
        dx[r] = fmaf(fr + a.b3[r], gate[r], bias);
      }
      float klv = -(a.accum6[(size_t)p * 6 + 3] * gate[0] +
                    a.accum6[(size_t)p * 6 + 4] * gate[1] +
                    a.accum6[(size_t)p * 6 + 5] * gate[2]);
      int m = a.mode_prev;
      if (m == 0) {
        o0 = xc0 + 0.5f * dt * dx[0]; o1 = xc1 + 0.5f * dt * dx[1]; o2 = xc2 + 0.5f * dt * dx[2];
        a.kx[p * 3] = dx[0]; a.kx[p * 3 + 1] = dx[1]; a.kx[p * 3 + 2] = dx[2];
        a.kl[p] = klv;
      } else if (m == 1) {
        o0 = xc0 + 0.5f * dt * dx[0]; o1 = xc1 + 0.5f * dt * dx[1]; o2 = xc2 + 0.5f * dt * dx[2];
        a.kx[p * 3] += 2.f * dx[0]; a.kx[p * 3 + 1] += 2.f * dx[1]; a.kx[p * 3 + 2] += 2.f * dx[2];
        a.kl[p] += 2.f * klv;
      } else if (m == 2) {
        o0 = xc0 + dt * dx[0]; o1 = xc1 + dt * dx[1]; o2 = xc2 + dt * dx[2];
        a.kx[p * 3] += 2.f * dx[0]; a.kx[p * 3 + 1] += 2.f * dx[1]; a.kx[p * 3 + 2] += 2.f * dx[2];
        a.kl[p] += 2.f * klv;
      } else {
        float sc = dt * (1.f / 6.f);
        o0 = xc0 + sc * (a.kx[p * 3] + dx[0]);
        o1 = xc1 + sc * (a.kx[p * 3 + 1] + dx[1]);
        o2 = xc2 + sc * (a.kx[p * 3 + 2] + dx[2]);
        a.x_cur[p * 3] = o0; a.x_cur[p * 3 + 1] = o1; a.x_cur[p * 3 + 2] = o2;
        a.lp_state[p] += sc * (a.kl[p] + klv);
      }
    }
    xe[tid][0] = o0; xe[tid][1] = o1; xe[tid][2] = o2;
  }
  __syncthreads();

  float t = a.ts_cur * dt;

  // ---- layer0: 32 threads per point, 16 cols each -> H1 (fp8) in LDS
  {
    float x0 = xe[pl0][0], x1 = xe[pl0][1], x2 = xe[pl0][2];
    u16x8 gcv[4] = {gc0, gc1, gc2, gc3};
    #pragma unroll
    for (int cc = 0; cc < 4; ++cc) {
      u16x8 v = gcv[cc];
      float hk[4], d0k[4], d1k[4], d2k[4];
      #pragma unroll
      for (int k = 0; k < 4; ++k) {
        int o = base_o + cc * 4 + k;
        f32x4 e = *(const f32x4*)(a.E0 + (size_t)o * 8);
        f32x2 e2 = *(const f32x2*)(a.E0 + (size_t)o * 8 + 4);
        float u = fmaf(e[0], x0, fmaf(e[1], x1, e[2] * x2)) + e[3];
        float gate = sigf(bf2f(v[2 * k]) + t * e2[0]);
        float bias = bf2f(v[2 * k + 1]) + t * e2[1];
        float z = fmaf(u, gate, bias);
        float h = fast_tanh(z);
        float wm = (1.f - h * h) * gate * TS;
        hk[k] = h;
        d0k[k] = wm * e[0];
        d1k[k] = wm * e[1];
        d2k[k] = wm * e[2];
      }
      size_t hb = (size_t)(pl0 * 4) * HSTRB + base_o + cc * 4;
      *(unsigned*)(Hs + hb) = pk4_f8(hk[0], hk[1], hk[2], hk[3]);
      *(unsigned*)(Hs + hb + HSTRB) = pk4_f8(d0k[0], d0k[1], d0k[2], d0k[3]);
      *(unsigned*)(Hs + hb + 2 * HSTRB) = pk4_f8(d1k[0], d1k[1], d1k[2], d1k[3]);
      *(unsigned*)(Hs + hb + 3 * HSTRB) = pk4_f8(d2k[0], d2k[1], d2k[2], d2k[3]);
    }
  }

  // ---- prefetch epilogue-1 gate dwords (hidden behind GEMM1)
  unsigned g1v[4][4];
  #pragma unroll
  for (int j = 0; j < 4; ++j)
    #pragma unroll
    for (int i = 0; i < 4; ++i) {
      int n = n0 + j * 16 + lr;
      int p = p0 + i * 4 + quad;
      g1v[j][i] = *(const unsigned*)(a.GBi1 + (size_t)p * 1024 + 2 * n);
    }
  __syncthreads();   // H1 visible to all waves

  // ---- layer1 GEMM: register-pipelined W, NO barriers
  f32x4 acc[4][4];
  #pragma unroll
  for (int i = 0; i < 4; ++i)
    #pragma unroll
    for (int j = 0; j < 4; ++j)
      #pragma unroll
      for (int r = 0; r < 4; ++r) acc[i][j][r] = 0.f;
  {
    #pragma unroll 1
    for (int c = 0; c < 16; ++c) {
      const u8* nsrc = (c < 15) ? (w1l + (size_t)(c + 1) * 16384) : w2l;
      #pragma unroll
      for (int j = 0; j < 4; ++j) bn[j] = *(const i64*)(nsrc + (size_t)j * 512);
      int k0 = c * 32;
      i64 af[4];
      #pragma unroll
      for (int i = 0; i < 4; ++i)
        af[i] = *(const i64*)(Hs + (size_t)(i * 16 + lr) * HSTRB + k0 + quad * 8);
      #pragma unroll
      for (int i = 0; i < 4; ++i)
        #pragma unroll
        for (int j = 0; j < 4; ++j)
          acc[i][j] = __builtin_amdgcn_mfma_f32_16x16x32_fp8_fp8(af[i], bc[j], acc[i][j], 0, 0, 0);
      #pragma unroll
      for (int j = 0; j < 4; ++j) bc[j] = bn[j];
    }
  }
  __syncthreads();   // all H1 reads done -> safe to overwrite

  // ---- epilogue1 -> H2 (fp8) in same LDS (FULLY unrolled)
  #pragma unroll
  for (int j = 0; j < 4; ++j) {
    int n = n0 + j * 16 + lr;
    f32x4 e1 = *(const f32x4*)(a.E1 + (size_t)n * 4);
    #pragma unroll
    for (int i = 0; i < 4; ++i) {
      unsigned d = g1v[j][i];
      float gate = sigf(bf2f((u16)(d & 0xffffu)) + t * e1[1]);
      float bias = bf2f((u16)(d >> 16)) + t * e1[2];
      f32x4 u = acc[i][j];
      float z = fmaf(u[0] + e1[0], gate, bias);
      float h = fast_tanh(z);
      float wmf = (1.f - h * h) * gate;
      int row = i * 16 + quad * 4;
      Hs[(size_t)row * HSTRB + n] = f2f8(h);
      Hs[(size_t)(row + 1) * HSTRB + n] = f2f8(u[1] * wmf);
      Hs[(size_t)(row + 2) * HSTRB + n] = f2f8(u[2] * wmf);
      Hs[(size_t)(row + 3) * HSTRB + n] = f2f8(u[3] * wmf);
    }
  }

  // ---- prefetch epilogue-2 gate dwords (hidden behind GEMM2)
  unsigned g2v[4][4];
  #pragma unroll
  for (int j = 0; j < 4; ++j)
    #pragma unroll
    for (int i = 0; i < 4; ++i) {
      int n = n0 + j * 16 + lr;
      int p = p0 + i * 4 + quad;
      g2v[j][i] = *(const unsigned*)(a.GBi2 + (size_t)p * 1024 + 2 * n);
    }
  __syncthreads();   // H2 visible; bc already holds W2 chunk 0

  // ---- layer2 GEMM: register-pipelined W, NO barriers
  #pragma unroll
  for (int i = 0; i < 4; ++i)
    #pragma unroll
    for (int j = 0; j < 4; ++j)
      #pragma unroll
      for (int r = 0; r < 4; ++r) acc[i][j][r] = 0.f;
  {
    #pragma unroll 1
    for (int c = 0; c < 16; ++c) {
      if (c < 15) {
        const u8* nsrc = w2l + (size_t)(c + 1) * 16384;
        #pragma unroll
        for (int j = 0; j < 4; ++j) bn[j] = *(const i64*)(nsrc + (size_t)j * 512);
      }
      int k0 = c * 32;
      i64 af[4];
      #pragma unroll
      for (int i = 0; i < 4; ++i)
        af[i] = *(const i64*)(Hs + (size_t)(i * 16 + lr) * HSTRB + k0 + quad * 8);
      #pragma unroll
      for (int i = 0; i < 4; ++i)
        #pragma unroll
        for (int j = 0; j < 4; ++j)
          acc[i][j] = __builtin_amdgcn_mfma_f32_16x16x32_fp8_fp8(af[i], bc[j], acc[i][j], 0, 0, 0);
      if (c < 15) {
        #pragma unroll
        for (int j = 0; j < 4; ++j) bc[j] = bn[j];
      }
    }
  }

  // ---- epilogue2: gate/tanh + project onto W3 -> 6 partials per point
  #pragma unroll
  for (int i = 0; i < 4; ++i) {
    float v0 = 0.f, v1 = 0.f, v2 = 0.f, v3 = 0.f, v4 = 0.f, v5 = 0.f;
    int pl = i * 4 + quad;
    #pragma unroll
    for (int j = 0; j < 4; ++j) {
      int n = n0 + j * 16 + lr;
      f32x4 ea = *(const f32x4*)(a.E2 + (size_t)n * 8);
      f32x2 eb = *(const f32x2*)(a.E2 + (size_t)n * 8 + 4);
      unsigned d = g2v[j][i];
      float gate = sigf(bf2f((u16)(d & 0xffffu)) + t * ea[1]);
      float bias = bf2f((u16)(d >> 16)) + t * ea[2];
      f32x4 u = acc[i][j];
      float z = fmaf(u[0] + ea[0], gate, bias);
      float h = fast_tanh(z);
      float wmf = (1.f - h * h) * gate;
      float w30 = ea[3], w31 = eb[0], w32 = eb[1];
      v0 = fmaf(h, w30, v0);
      v1 = fmaf(h, w31, v1);
      v2 = fmaf(h, w32, v2);
      v3 = fmaf(u[1] * wmf, w30, v3);
      v4 = fmaf(u[2] * wmf, w31, v4);
      v5 = fmaf(u[3] * wmf, w32, v5);
    }
    #pragma unroll
    for (int mask = 1; mask <= 8; mask <<= 1) {
      v0 += __shfl_xor(v0, mask);
      v1 += __shfl_xor(v1, mask);
      v2 += __shfl_xor(v2, mask);
      v3 += __shfl_xor(v3, mask);
      v4 += __shfl_xor(v4, mask);
      v5 += __shfl_xor(v5, mask);
    }
    // tangent streams carry TS scale through both GEMMs -> undo here
    float val = (lr == 0) ? v0 : (lr == 1) ? v1 : (lr == 2) ? v2
              : (lr == 3) ? v3 * (1.f / TS) : (lr == 4) ? v4 * (1.f / TS)
              : v5 * (1.f / TS);
    if (lr < 6) part[w][pl][lr] = val;
  }
  __syncthreads();

  if (tid < 96) {
    int pt = tid / 6, d = tid - pt * 6;
    float sum = 0.f;
    #pragma unroll
    for (int ww = 0; ww < 8; ++ww) sum += part[ww][pt][d];
    a.accum6[(size_t)(p0 + pt) * 6 + d] = sum;
  }
}

// ---------------------------------------------------------------- finalize + lp reduce (merged)
// 4 blocks x 256 threads; thread t of block b finalizes points p = b*2048 + t*8 .. +7,
// accumulates their lp, then block-reduces and writes out[b].
struct FinArgs {
  const float* sqrtT;
  const float* accum6;
  const float *G3, *B3, *Wg3, *Wb3, *b3;
  const float *x_cur, *kx, *kl, *lp_state;
  const float *m2, *v2, *lg2, *be2;
  const float *v1, *lg1;
  float* out_x;
  float* out_lp;
};
__global__ void finalize_kernel(FinArgs a) {
  int b = blockIdx.x, tid = threadIdx.x;
  float s0 = a.sqrtT[0];
  float dt = s0 * s0 * (1.f / 3.f);
  float tp = 3.f * dt;
  float sc = dt * (1.f / 6.f);
  float lpsum = 0.f;
  #pragma unroll 1
  for (int q = 0; q < 8; ++q) {
    int p = b * 2048 + tid * 8 + q;
    float dx[3], gate[3];
    #pragma unroll
    for (int r = 0; r < 3; ++r) {
      float fr = a.accum6[(size_t)p * 6 + r];
      gate[r] = sigf(a.G3[p * 3 + r] + tp * a.Wg3[r * 65]);
      float bias = a.B3[p * 3 + r] + tp * a.Wb3[r * 65];
      dx[r] = fmaf(fr + a.b3[r], gate[r], bias);
    }
    float klv = -(a.accum6[(size_t)p * 6 + 3] * gate[0] +
                  a.accum6[(size_t)p * 6 + 4] * gate[1] +
                  a.accum6[(size_t)p * 6 + 5] * gate[2]);
    #pragma unroll
    for (int r = 0; r < 3; ++r) {
      float xf = a.x_cur[p * 3 + r] + sc * (a.kx[p * 3 + r] + dx[r]);
      a.out_x[p * 3 + r] = (xf - a.m2[r]) * __expf(a.lg2[r]) * rsqrtf(a.v2[r] + BN_EPS) + a.be2[r];
    }
    lpsum += a.lp_state[p] + sc * (a.kl[p] + klv);
  }
  __shared__ float red[256];
  red[tid] = lpsum;
  __syncthreads();
  for (int w = 128; w > 0; w >>= 1) {
    if (tid < w) red[tid] += red[tid + w];
    __syncthreads();
  }
  if (tid == 0) {
    float ld = 0.f;
    for (int d = 0; d < 3; ++d) {
      ld += a.lg1[d] - 0.5f * logf(a.v1[d] + BN_EPS);
      ld += a.lg2[d] - 0.5f * logf(a.v2[d] + BN_EPS);
    }
    a.out_lp[b] = red[0] - 2048.f * ld;
  }
}

// ---------------------------------------------------------------- launch
extern "C" void kernel_launch(void* const* d_in, const int* in_sizes, int n_in,
                              void* d_out, int out_size, void* d_ws, size_t ws_size,
                              hipStream_t stream) {
  const float* x        = (const float*)d_in[0];
  const float* c        = (const float*)d_in[1];
  const float* bn1_mean = (const float*)d_in[2];
  const float* bn1_var  = (const float*)d_in[3];
  const float* bn1_lg   = (const float*)d_in[4];
  const float* bn1_beta = (const float*)d_in[5];
  const float* bn2_mean = (const float*)d_in[6];
  const float* bn2_var  = (const float*)d_in[7];
  const float* bn2_lg   = (const float*)d_in[8];
  const float* bn2_beta = (const float*)d_in[9];
  const float* sqrtT    = (const float*)d_in[10];
  const float* W0  = (const float*)d_in[11];
  const float* b0  = (const float*)d_in[12];
  const float* Wg0 = (const float*)d_in[13];
  const float* bg0 = (const float*)d_in[14];
  const float* Wb0 = (const float*)d_in[15];
  const float* W1  = (const float*)d_in[16];
  const float* b1  = (const float*)d_in[17];
  const float* Wg1 = (const float*)d_in[18];
  const float* bg1 = (const float*)d_in[19];
  const float* Wb1 = (const float*)d_in[20];
  const float* W2  = (const float*)d_in[21];
  const float* b2  = (const float*)d_in[22];
  const float* Wg2 = (const float*)d_in[23];
  const float* bg2 = (const float*)d_in[24];
  const float* Wb2 = (const float*)d_in[25];
  const float* W3  = (const float*)d_in[26];
  const float* b3  = (const float*)d_in[27];
  const float* Wg3 = (const float*)d_in[28];
  const float* bg3 = (const float*)d_in[29];
  const float* Wb3 = (const float*)d_in[30];

  char* base = (char*)d_ws;
  size_t off = 0;
  auto alloc = [&](size_t bytes) -> void* {
    void* pp = base + off;
    off += (bytes + 255) & ~(size_t)255;
    return pp;
  };
  u8* W1s = (u8*)alloc((size_t)512 * 512);
  u8* W2s = (u8*)alloc((size_t)512 * 512);
  u16* cb  = (u16*)alloc((size_t)PTS * 64 * 2);
  u16* Wpack = (u16*)alloc((size_t)6 * 512 * 64 * 2);
  float* bias_pack = (float*)alloc((size_t)3072 * 4);
  u16* GBi = (u16*)alloc((size_t)3 * PTS * 1024 * 2);
  const size_t SZi = (size_t)PTS * 1024;
  u16* GBi0 = GBi;
  u16* GBi1 = GBi + SZi;
  u16* GBi2 = GBi + 2 * SZi;
  float* G3f = (float*)alloc((size_t)PTS * 3 * 4);
  float* B3f = (float*)alloc((size_t)PTS * 3 * 4);
  float* E0 = (float*)alloc((size_t)512 * 8 * 4);
  float* E1 = (float*)alloc((size_t)512 * 4 * 4);
  float* E2 = (float*)alloc((size_t)512 * 8 * 4);
  float* accum6   = (float*)alloc((size_t)PTS * 6 * 4);
  float* x_cur    = (float*)alloc((size_t)PTS * 3 * 4);
  float* kx       = (float*)alloc((size_t)PTS * 3 * 4);
  float* kl       = (float*)alloc((size_t)PTS * 4);
  float* lp_state = (float*)alloc((size_t)PTS * 4);
  (void)ws_size; (void)in_sizes; (void)n_in; (void)out_size;

  PrepArgs pa{W1, W2, W1s, W2s, c, cb, Wg0, Wg1, Wg2, Wb0, Wb1, Wb2,
              bg0, bg1, bg2, Wpack, bias_pack, x, bn1_mean, bn1_var,
              bn1_lg, bn1_beta, x_cur, lp_state, Wg3, bg3, Wb3, G3f, B3f,
              W0, b0, b1, b2, W3, E0, E1, E2};
  prep_kernel<<<2048, 256, 0, stream>>>(pa);

  GatesGemmArgs gg{cb, Wpack, bias_pack, GBi};
  gates_gemm<<<dim3(64, 24), 256, 0, stream>>>(gg);

  auto ts_of = [](int s) -> float {
    static const float frac[4] = {0.f, 0.5f, 0.5f, 1.f};
    return (float)(s >> 2) + frac[s & 3];
  };

  for (int s = 0; s < 12; ++s) {
    StageArgs sa{sqrtT, (s == 0) ? 0.f : ts_of(s - 1), ts_of(s),
                 (s == 0) ? -1 : ((s - 1) & 3), accum6,
                 G3f, B3f, Wg3, Wb3, b3, x_cur, kx, kl, lp_state,
                 GBi0, GBi1, GBi2, E0, E1, E2, W1s, W2s};
    stage_kernel<<<PTS / 16, 512, 0, stream>>>(sa);
  }

  FinArgs fa{sqrtT, accum6, G3f, B3f, Wg3, Wb3, b3, x_cur, kx, kl,
             lp_state, bn2_mean, bn2_var, bn2_lg, bn2_beta,
             bn1_var, bn1_lg, (float*)d_out, (float*)d_out + PTS * 3};
  finalize_kernel<<<4, 256, 0, stream>>>(fa);
}

// Round 17
// 680.114 us; speedup vs baseline: 1.1018x; 1.0057x over previous
//
#include <hip/hip_runtime.h>
#include <hip/hip_fp8.h>

#define PTS 8192          // B*N = 4*2048 points
#define HDIM 512
#define BN_EPS 1e-4f
#define HSTRB 528         // LDS row stride in BYTES (fp8 cols)
#define TS 256.0f         // tangent-stream scale (keeps JVP streams out of e4m3 subnormals)

typedef unsigned short u16;
typedef unsigned char u8;
typedef long long i64;
typedef u16 u16x8 __attribute__((ext_vector_type(8)));
typedef short s16x8 __attribute__((ext_vector_type(8)));
typedef float f32x4 __attribute__((ext_vector_type(4)));
typedef float f32x2 __attribute__((ext_vector_type(2)));

__device__ __forceinline__ float bf2f(u16 u) {
  unsigned x = ((unsigned)u) << 16;
  return __builtin_bit_cast(float, x);
}
__device__ __forceinline__ u16 f2bf(float f) {
  unsigned x = __builtin_bit_cast(unsigned, f);
  x += 0x7fffu + ((x >> 16) & 1u);
  return (u16)(x >> 16);
}
// native HW fp8 convert (v_cvt_pk_fp8_f32; OCP e4m3 on gfx950)
__device__ __forceinline__ u8 f2f8(float x) {
  int v = __builtin_amdgcn_cvt_pk_fp8_f32(x, x, 0, false);
  return (u8)(v & 0xff);
}
__device__ __forceinline__ unsigned pk4_f8(float a, float b, float c, float d) {
  int v = __builtin_amdgcn_cvt_pk_fp8_f32(a, b, 0, false);
  v = __builtin_amdgcn_cvt_pk_fp8_f32(c, d, v, true);
  return (unsigned)v;
}
__device__ __forceinline__ float sigf(float x) {
  return __builtin_amdgcn_rcpf(1.f + __expf(-x));
}
__device__ __forceinline__ float fast_tanh(float x) {
  float e = __expf(2.f * x);
  return 1.f - 2.f * __builtin_amdgcn_rcpf(e + 1.f);
}
__device__ __forceinline__ void gl2lds16(const u16* g, u16* l) {
  __builtin_amdgcn_global_load_lds(
      (const __attribute__((address_space(1))) void*)g,
      (__attribute__((address_space(3))) void*)l, 16, 0, 0);
}

// ---------------------------------------------------------------- prep
struct PrepArgs {
  const float *W1, *W2;
  u8 *W1s, *W2s;       // fp8 e4m3, frag-order: [16 chunks][8 waves][4 j][64 lanes][8 B]
  const float* c;
  u16* cb;
  const float *Wg0, *Wg1, *Wg2, *Wb0, *Wb1, *Wb2;
  const float *bg0, *bg1, *bg2;
  u16* Wpack;          // [6*512][64] bf16
  float* bias_pack;    // [3072]
  const float *x, *m1, *v1, *lg1, *be1;
  float *x_cur, *lp_state;
  const float *Wg3, *bg3, *Wb3;
  float *G3, *B3;
  const float *W0, *b0, *b1, *b2, *W3;
  float *E0, *E1, *E2;   // packed epilogue params
};
__global__ void prep_kernel(PrepArgs a) {
  int i = blockIdx.x * 256 + threadIdx.x;   // 0 .. 524287
  if (i < 512 * 512) {
    int n = i >> 9, k = i & 511;
    int c = k >> 5, kin = k & 31, q = kin >> 3, b = kin & 7;
    int w = n >> 6, nin = n & 63, j = nin >> 4, lr = nin & 15;
    size_t d = ((((size_t)(c * 8 + w) * 4 + j) * 64) + (q * 16 + lr)) * 8 + b;
    a.W1s[d] = f2f8(a.W1[i]);
    a.W2s[d] = f2f8(a.W2[i]);
  }
  if (i < PTS * 64) a.cb[i] = f2bf(a.c[i]);
  if (i < 6 * 512 * 64) {
    int sec = i >> 15;
    int within = i & 32767;
    int o = within >> 6, k = within & 63;
    const float* src[6] = {a.Wg0, a.Wg1, a.Wg2, a.Wb0, a.Wb1, a.Wb2};
    a.Wpack[i] = f2bf(src[sec][o * 65 + 1 + k]);
  }
  if (i < 3072) {
    int sec = i >> 9, o = i & 511;
    const float* bgl[3] = {a.bg0, a.bg1, a.bg2};
    a.bias_pack[i] = (sec < 3) ? bgl[sec][o] : 0.f;
  }
  if (i < 512) {
    int o = i;
    a.E0[o * 8 + 0] = a.W0[o * 3];
    a.E0[o * 8 + 1] = a.W0[o * 3 + 1];
    a.E0[o * 8 + 2] = a.W0[o * 3 + 2];
    a.E0[o * 8 + 3] = a.b0[o];
    a.E0[o * 8 + 4] = a.Wg0[o * 65];
    a.E0[o * 8 + 5] = a.Wb0[o * 65];
    a.E0[o * 8 + 6] = 0.f; a.E0[o * 8 + 7] = 0.f;
    a.E1[o * 4 + 0] = a.b1[o];
    a.E1[o * 4 + 1] = a.Wg1[o * 65];
    a.E1[o * 4 + 2] = a.Wb1[o * 65];
    a.E1[o * 4 + 3] = 0.f;
    a.E2[o * 8 + 0] = a.b2[o];
    a.E2[o * 8 + 1] = a.Wg2[o * 65];
    a.E2[o * 8 + 2] = a.Wb2[o * 65];
    a.E2[o * 8 + 3] = a.W3[o];
    a.E2[o * 8 + 4] = a.W3[512 + o];
    a.E2[o * 8 + 5] = a.W3[1024 + o];
    a.E2[o * 8 + 6] = 0.f; a.E2[o * 8 + 7] = 0.f;
  }
  if (i < PTS * 3) {
    int d = i % 3;
    a.x_cur[i] = (a.x[i] - a.m1[d]) * __expf(a.lg1[d]) * rsqrtf(a.v1[d] + BN_EPS) + a.be1[d];
  }
  if (i < PTS) a.lp_state[i] = 0.f;
  {
    int lane = threadIdx.x & 63;
    int p = (blockIdx.x * 256 + threadIdx.x) >> 6;   // 0..8191
    float cv = a.c[(size_t)p * 64 + lane];
    float ag[3], ab[3];
    #pragma unroll
    for (int o = 0; o < 3; ++o) {
      ag[o] = cv * a.Wg3[o * 65 + 1 + lane];
      ab[o] = cv * a.Wb3[o * 65 + 1 + lane];
    }
    #pragma unroll
    for (int off = 32; off > 0; off >>= 1) {
      #pragma unroll
      for (int o = 0; o < 3; ++o) {
        ag[o] += __shfl_xor(ag[o], off);
        ab[o] += __shfl_xor(ab[o], off);
      }
    }
    if (lane == 0) {
      #pragma unroll
      for (int o = 0; o < 3; ++o) {
        a.G3[p * 3 + o] = ag[o] + a.bg3[o];
        a.B3[p * 3 + o] = ab[o];
      }
    }
  }
}

// ---------------------------------------------------------------- gates GEMM (bf16, proven)
struct GatesGemmArgs {
  const u16 *A, *W;
  const float* bias;
  u16* GBi;                // [3][8192][1024] interleaved
};
__global__ __launch_bounds__(256) void gates_gemm(GatesGemmArgs a) {
  __shared__ u16 As[128 * 32];
  __shared__ u16 Bs[128 * 32];
  int tid = threadIdx.x;
  int m0 = blockIdx.x * 128, n0 = blockIdx.y * 128;
  int wave = tid >> 6, lane = tid & 63;
  int wm = (wave & 1) * 64, wn = (wave >> 1) * 64;
  int lr = lane & 15, quad = lane >> 4;

  int rowS = tid >> 2, colS = (tid & 3) * 8;
  const u16* gA0 = a.A + (size_t)(m0 + rowS) * 64 + colS;
  const u16* gB0 = a.W + (size_t)(n0 + rowS) * 64 + colS;
  u16* sA0 = &As[tid * 8];
  u16* sA1 = &As[2048 + tid * 8];
  u16* sB0 = &Bs[tid * 8];
  u16* sB1 = &Bs[2048 + tid * 8];

  f32x4 acc[4][4];
  #pragma unroll
  for (int i = 0; i < 4; ++i)
    #pragma unroll
    for (int j = 0; j < 4; ++j)
      #pragma unroll
      for (int r = 0; r < 4; ++r) acc[i][j][r] = 0.f;

  for (int k0 = 0; k0 < 64; k0 += 32) {
    if (k0) __syncthreads();
    gl2lds16(gA0 + k0, sA0);
    gl2lds16(gA0 + (size_t)64 * 64 + k0, sA1);
    gl2lds16(gB0 + k0, sB0);
    gl2lds16(gB0 + (size_t)64 * 64 + k0, sB1);
    __syncthreads();
    s16x8 af[4], bfr[4];
    #pragma unroll
    for (int i = 0; i < 4; ++i)
      af[i] = *(const s16x8*)&As[(wm + i * 16 + lr) * 32 + quad * 8];
    #pragma unroll
    for (int j = 0; j < 4; ++j)
      bfr[j] = *(const s16x8*)&Bs[(wn + j * 16 + lr) * 32 + quad * 8];
    #pragma unroll
    for (int i = 0; i < 4; ++i)
      #pragma unroll
      for (int j = 0; j < 4; ++j)
        acc[i][j] = __builtin_amdgcn_mfma_f32_16x16x32_bf16(af[i], bfr[j], acc[i][j], 0, 0, 0);
  }

  #pragma unroll
  for (int j = 0; j < 4; ++j) {
    int n = n0 + wn + j * 16 + lr;
    int sec = n >> 9, col = n & 511;
    int l = (sec < 3) ? sec : sec - 3;
    int off = col * 2 + ((sec < 3) ? 0 : 1);
    float bv = a.bias[n];
    u16* outp = a.GBi + (size_t)l * PTS * 1024 + off;
    #pragma unroll
    for (int i = 0; i < 4; ++i) {
      int mrow = m0 + wm + i * 16 + quad * 4;
      #pragma unroll
      for (int r = 0; r < 4; ++r)
        outp[(size_t)(mrow + r) * 1024] = f2bf(acc[i][j][r] + bv);
    }
  }
}

// ---------------------------------------------------------------- per-stage kernel
// 512 blocks x 512 threads (8 waves); block owns 16 points (64 m-rows).
// Register-pipelined frag-order W (no K-loop barriers). This round:
//  - fold computed REDUNDANTLY by all 32 threads of each point group (kills
//    barrier 1 + xe LDS; side-effect writes by group leader only)
//  - Hs double-buffered (H1 in A, H2 in B) kills the GEMM1->epi1 barrier.
// 3 barriers/stage total.
struct StageArgs {
  const float* sqrtT;
  float ts_prev, ts_cur;
  int mode_prev;             // -1 none, 0,1,2 stage folds, 3 step-end fold
  float* accum6;             // [PTS][6]
  const float *G3, *B3, *Wg3, *Wb3, *b3;
  float *x_cur, *kx, *kl, *lp_state;
  const u16 *GBi0, *GBi1, *GBi2;   // interleaved gate tables [PTS][1024]
  const float *E0, *E1, *E2;       // packed params
  const u8 *W1s, *W2s;             // fp8 weights frag-order [16][8][4][64][8]
};

__global__ __launch_bounds__(512, 4) void stage_kernel(StageArgs a) {
  __shared__ __align__(16) u8 HsA[64 * HSTRB];    // 33.8 KB H1
  __shared__ __align__(16) u8 HsB[64 * HSTRB];    // 33.8 KB H2
  __shared__ float part[8][16][6];
  int tid = threadIdx.x;
  int w = tid >> 6, lane = tid & 63, lr = lane & 15, quad = lane >> 4;
  int n0 = w * 64;
  int p0 = blockIdx.x * 16;
  float s0 = a.sqrtT[0];
  float dt = s0 * s0 * (1.f / 3.f);

  // wave-local W slice base pointers (frag-order)
  const u8* w1l = a.W1s + (size_t)w * 2048 + (size_t)lane * 8;
  const u8* w2l = a.W2s + (size_t)w * 2048 + (size_t)lane * 8;

  // ---- preload W1 chunk 0 into registers (L2 latency overlaps fold + L0)
  i64 bc[4], bn[4];
  #pragma unroll
  for (int j = 0; j < 4; ++j) bc[j] = *(const i64*)(w1l + (size_t)j * 512);

  // ---- issue L0 gate loads EARLY (independent of fold)
  int pl0 = tid >> 5;
  int base_o = (tid & 31) * 16;
  const u16* g0row = a.GBi0 + (size_t)(p0 + pl0) * 1024 + 2 * base_o;
  u16x8 gc0 = *(const u16x8*)(g0row);
  u16x8 gc1 = *(const u16x8*)(g0row + 8);
  u16x8 gc2 = *(const u16x8*)(g0row + 16);
  u16x8 gc3 = *(const u16x8*)(g0row + 24);

  // ---- fold previous stage: ALL 32 threads of a point group compute it
  // (redundant, L1-broadcast reads); leader does the global side effects.
  float xv0, xv1, xv2;
  {
    int p = p0 + pl0;
    bool ldr = (tid & 31) == 0;
    float xc0 = a.x_cur[p * 3], xc1 = a.x_cur[p * 3 + 1], xc2 = a.x_cur[p * 3 + 2];
    xv0 = xc0; xv1 = xc1; xv2 = xc2;
    if (a.mode_prev >= 0) {
      float tp = a.ts_prev * dt;
      float dx[3], gate[3];
      #pragma unroll
      for (int r = 0; r < 3; ++r) {
        float fr = a.accum6[(size_t)p * 6 + r];
        gate[r] = sigf(a.G3[p * 3 + r] + tp * a.Wg3[r * 65]);
        float bias = a.B3[p * 3 + r] + tp * a.Wb3[r * 65];
        dx[r] = fmaf(fr + a.b3[r], gate[r], bias);
      }
      float klv = -(a.accum6[(size_t)p * 6 + 3] * gate[0] +
                    a.accum6[(size_t)p * 6 + 4] * gate[1] +
                    a.accum6[(size_t)p * 6 + 5] * gate[2]);
      int m = a.mode_prev;
      if (m == 0) {
        xv0 = xc0 + 0.5f * dt * dx[0]; xv1 = xc1 + 0.5f * dt * dx[1]; xv2 = xc2 + 0.5f * dt * dx[2];
        if (ldr) {
          a.kx[p * 3] = dx[0]; a.kx[p * 3 + 1] = dx[1]; a.kx[p * 3 + 2] = dx[2];
          a.kl[p] = klv;
        }
      } else if (m == 1) {
        xv0 = xc0 + 0.5f * dt * dx[0]; xv1 = xc1 + 0.5f * dt * dx[1]; xv2 = xc2 + 0.5f * dt * dx[2];
        if (ldr) {
          a.kx[p * 3] += 2.f * dx[0]; a.kx[p * 3 + 1] += 2.f * dx[1]; a.kx[p * 3 + 2] += 2.f * dx[2];
          a.kl[p] += 2.f * klv;
        }
      } else if (m == 2) {
        xv0 = xc0 + dt * dx[0]; xv1 = xc1 + dt * dx[1]; xv2 = xc2 + dt * dx[2];
        if (ldr) {
          a.kx[p * 3] += 2.f * dx[0]; a.kx[p * 3 + 1] += 2.f * dx[1]; a.kx[p * 3 + 2] += 2.f * dx[2];
          a.kl[p] += 2.f * klv;
        }
      } else {
        float sc = dt * (1.f / 6.f);
        xv0 = xc0 + sc * (a.kx[p * 3] + dx[0]);
        xv1 = xc1 + sc * (a.kx[p * 3 + 1] + dx[1]);
        xv2 = xc2 + sc * (a.kx[p * 3 + 2] + dx[2]);
        if (ldr) {
          a.x_cur[p * 3] = xv0; a.x_cur[p * 3 + 1] = xv1; a.x_cur[p * 3 + 2] = xv2;
          a.lp_state[p] += sc * (a.kl[p] + klv);
        }
      }
    }
  }

  float t = a.ts_cur * dt;

  // ---- layer0: 32 threads per point, 16 cols each -> H1 (fp8) into HsA
  {
    u16x8 gcv[4] = {gc0, gc1, gc2, gc3};
    #pragma unroll
    for (int cc = 0; cc < 4; ++cc) {
      u16x8 v = gcv[cc];
      float hk[4], d0k[4], d1k[4], d2k[4];
      #pragma unroll
      for (int k = 0; k < 4; ++k) {
        int o = base_o + cc * 4 + k;
        f32x4 e = *(const f32x4*)(a.E0 + (size_t)o * 8);
        f32x2 e2 = *(const f32x2*)(a.E0 + (size_t)o * 8 + 4);
        float u = fmaf(e[0], xv0, fmaf(e[1], xv1, e[2] * xv2)) + e[3];
        float gate = sigf(bf2f(v[2 * k]) + t * e2[0]);
        float bias = bf2f(v[2 * k + 1]) + t * e2[1];
        float z = fmaf(u, gate, bias);
        float h = fast_tanh(z);
        float wm = (1.f - h * h) * gate * TS;
        hk[k] = h;
        d0k[k] = wm * e[0];
        d1k[k] = wm * e[1];
        d2k[k] = wm * e[2];
      }
      size_t hb = (size_t)(pl0 * 4) * HSTRB + base_o + cc * 4;
      *(unsigned*)(HsA + hb) = pk4_f8(hk[0], hk[1], hk[2], hk[3]);
      *(unsigned*)(HsA + hb + HSTRB) = pk4_f8(d0k[0], d0k[1], d0k[2], d0k[3]);
      *(unsigned*)(HsA + hb + 2 * HSTRB) = pk4_f8(d1k[0], d1k[1], d1k[2], d1k[3]);
      *(unsigned*)(HsA + hb + 3 * HSTRB) = pk4_f8(d2k[0], d2k[1], d2k[2], d2k[3]);
    }
  }

  // ---- prefetch epilogue-1 gate dwords (hidden behind GEMM1)
  unsigned g1v[4][4];
  #pragma unroll
  for (int j = 0; j < 4; ++j)
    #pragma unroll
    for (int i = 0; i < 4; ++i) {
      int n = n0 + j * 16 + lr;
      int p = p0 + i * 4 + quad;
      g1v[j][i] = *(const unsigned*)(a.GBi1 + (size_t)p * 1024 + 2 * n);
    }
  __syncthreads();   // barrier 1: H1 visible to all waves

  // ---- layer1 GEMM: register-pipelined W, NO barriers
  f32x4 acc[4][4];
  #pragma unroll
  for (int i = 0; i < 4; ++i)
    #pragma unroll
    for (int j = 0; j < 4; ++j)
      #pragma unroll
      for (int r = 0; r < 4; ++r) acc[i][j][r] = 0.f;
  {
    #pragma unroll 1
    for (int c = 0; c < 16; ++c) {
      const u8* nsrc = (c < 15) ? (w1l + (size_t)(c + 1) * 16384) : w2l;
      #pragma unroll
      for (int j = 0; j < 4; ++j) bn[j] = *(const i64*)(nsrc + (size_t)j * 512);
      int k0 = c * 32;
      i64 af[4];
      #pragma unroll
      for (int i = 0; i < 4; ++i)
        af[i] = *(const i64*)(HsA + (size_t)(i * 16 + lr) * HSTRB + k0 + quad * 8);
      #pragma unroll
      for (int i = 0; i < 4; ++i)
        #pragma unroll
        for (int j = 0; j < 4; ++j)
          acc[i][j] = __builtin_amdgcn_mfma_f32_16x16x32_fp8_fp8(af[i], bc[j], acc[i][j], 0, 0, 0);
      #pragma unroll
      for (int j = 0; j < 4; ++j) bc[j] = bn[j];
    }
  }

  // ---- epilogue1 -> H2 (fp8) into HsB (no barrier needed: different buffer)
  #pragma unroll
  for (int j = 0; j < 4; ++j) {
    int n = n0 + j * 16 + lr;
    f32x4 e1 = *(const f32x4*)(a.E1 + (size_t)n * 4);
    #pragma unroll
    for (int i = 0; i < 4; ++i) {
      unsigned d = g1v[j][i];
      float gate = sigf(bf2f((u16)(d & 0xffffu)) + t * e1[1]);
      float bias = bf2f((u16)(d >> 16)) + t * e1[2];
      f32x4 u = acc[i][j];
      float z = fmaf(u[0] + e1[0], gate, bias);
      float h = fast_tanh(z);
      float wmf = (1.f - h * h) * gate;
      int row = i * 16 + quad * 4;
      HsB[(size_t)row * HSTRB + n] = f2f8(h);
      HsB[(size_t)(row + 1) * HSTRB + n] = f2f8(u[1] * wmf);
      HsB[(size_t)(row + 2) * HSTRB + n] = f2f8(u[2] * wmf);
      HsB[(size_t)(row + 3) * HSTRB + n] = f2f8(u[3] * wmf);
    }
  }

  // ---- prefetch epilogue-2 gate dwords (hidden behind GEMM2)
  unsigned g2v[4][4];
  #pragma unroll
  for (int j = 0; j < 4; ++j)
    #pragma unroll
    for (int i = 0; i < 4; ++i) {
      int n = n0 + j * 16 + lr;
      int p = p0 + i * 4 + quad;
      g2v[j][i] = *(const unsigned*)(a.GBi2 + (size_t)p * 1024 + 2 * n);
    }
  __syncthreads();   // barrier 2: H2 visible; bc already holds W2 chunk 0

  // ---- layer2 GEMM: register-pipelined W, NO barriers
  #pragma unroll
  for (int i = 0; i < 4; ++i)
    #pragma unroll
    for (int j = 0; j < 4; ++j)
      #pragma unroll
      for (int r = 0; r < 4; ++r) acc[i][j][r] = 0.f;
  {
    #pragma unroll 1
    for (int c = 0; c < 16; ++c) {
      if (c < 15) {
        const u8* nsrc = w2l + (size_t)(c + 1) * 16384;
        #pragma unroll
        for (int j = 0; j < 4; ++j) bn[j] = *(const i64*)(nsrc + (size_t)j * 512);
      }
      int k0 = c * 32;
      i64 af[4];
      #pragma unroll
      for (int i = 0; i < 4; ++i)
        af[i] = *(const i64*)(HsB + (size_t)(i * 16 + lr) * HSTRB + k0 + quad * 8);
      #pragma unroll
      for (int i = 0; i < 4; ++i)
        #pragma unroll
        for (int j = 0; j < 4; ++j)
          acc[i][j] = __builtin_amdgcn_mfma_f32_16x16x32_fp8_fp8(af[i], bc[j], acc[i][j], 0, 0, 0);
      if (c < 15) {
        #pragma unroll
        for (int j = 0; j < 4; ++j) bc[j] = bn[j];
      }
    }
  }

  // ---- epilogue2: gate/tanh + project onto W3 -> 6 partials per point
  #pragma unroll
  for (int i = 0; i < 4; ++i) {
    float v0 = 0.f, v1 = 0.f, v2 = 0.f, v3 = 0.f, v4 = 0.f, v5 = 0.f;
    int pl = i * 4 + quad;
    #pragma unroll
    for (int j = 0; j < 4; ++j) {
      int n = n0 + j * 16 + lr;
      f32x4 ea = *(const f32x4*)(a.E2 + (size_t)n * 8);
      f32x2 eb = *(const f32x2*)(a.E2 + (size_t)n * 8 + 4);
      unsigned d = g2v[j][i];
      float gate = sigf(bf2f((u16)(d & 0xffffu)) + t * ea[1]);
      float bias = bf2f((u16)(d >> 16)) + t * ea[2];
      f32x4 u = acc[i][j];
      float z = fmaf(u[0] + ea[0], gate, bias);
      float h = fast_tanh(z);
      float wmf = (1.f - h * h) * gate;
      float w30 = ea[3], w31 = eb[0], w32 = eb[1];
      v0 = fmaf(h, w30, v0);
      v1 = fmaf(h, w31, v1);
      v2 = fmaf(h, w32, v2);
      v3 = fmaf(u[1] * wmf, w30, v3);
      v4 = fmaf(u[2] * wmf, w31, v4);
      v5 = fmaf(u[3] * wmf, w32, v5);
    }
    #pragma unroll
    for (int mask = 1; mask <= 8; mask <<= 1) {
      v0 += __shfl_xor(v0, mask);
      v1 += __shfl_xor(v1, mask);
      v2 += __shfl_xor(v2, mask);
      v3 += __shfl_xor(v3, mask);
      v4 += __shfl_xor(v4, mask);
      v5 += __shfl_xor(v5, mask);
    }
    // tangent streams carry TS scale through both GEMMs -> undo here
    float val = (lr == 0) ? v0 : (lr == 1) ? v1 : (lr == 2) ? v2
              : (lr == 3) ? v3 * (1.f / TS) : (lr == 4) ? v4 * (1.f / TS)
              : v5 * (1.f / TS);
    if (lr < 6) part[w][pl][lr] = val;
  }
  __syncthreads();   // barrier 3: part visible

  if (tid < 96) {
    int pt = tid / 6, d = tid - pt * 6;
    float sum = 0.f;
    #pragma unroll
    for (int ww = 0; ww < 8; ++ww) sum += part[ww][pt][d];
    a.accum6[(size_t)(p0 + pt) * 6 + d] = sum;
  }
}

// ---------------------------------------------------------------- finalize + lp reduce (merged)
struct FinArgs {
  const float* sqrtT;
  const float* accum6;
  const float *G3, *B3, *Wg3, *Wb3, *b3;
  const float *x_cur, *kx, *kl, *lp_state;
  const float *m2, *v2, *lg2, *be2;
  const float *v1, *lg1;
  float* out_x;
  float* out_lp;
};
__global__ void finalize_kernel(FinArgs a) {
  int b = blockIdx.x, tid = threadIdx.x;
  float s0 = a.sqrtT[0];
  float dt = s0 * s0 * (1.f / 3.f);
  float tp = 3.f * dt;
  float sc = dt * (1.f / 6.f);
  float lpsum = 0.f;
  #pragma unroll 1
  for (int q = 0; q < 8; ++q) {
    int p = b * 2048 + tid * 8 + q;
    float dx[3], gate[3];
    #pragma unroll
    for (int r = 0; r < 3; ++r) {
      float fr = a.accum6[(size_t)p * 6 + r];
      gate[r] = sigf(a.G3[p * 3 + r] + tp * a.Wg3[r * 65]);
      float bias = a.B3[p * 3 + r] + tp * a.Wb3[r * 65];
      dx[r] = fmaf(fr + a.b3[r], gate[r], bias);
    }
    float klv = -(a.accum6[(size_t)p * 6 + 3] * gate[0] +
                  a.accum6[(size_t)p * 6 + 4] * gate[1] +
                  a.accum6[(size_t)p * 6 + 5] * gate[2]);
    #pragma unroll
    for (int r = 0; r < 3; ++r) {
      float xf = a.x_cur[p * 3 + r] + sc * (a.kx[p * 3 + r] + dx[r]);
      a.out_x[p * 3 + r] = (xf - a.m2[r]) * __expf(a.lg2[r]) * rsqrtf(a.v2[r] + BN_EPS) + a.be2[r];
    }
    lpsum += a.lp_state[p] + sc * (a.kl[p] + klv);
  }
  __shared__ float red[256];
  red[tid] = lpsum;
  __syncthreads();
  for (int w = 128; w > 0; w >>= 1) {
    if (tid < w) red[tid] += red[tid + w];
    __syncthreads();
  }
  if (tid == 0) {
    float ld = 0.f;
    for (int d = 0; d < 3; ++d) {
      ld += a.lg1[d] - 0.5f * logf(a.v1[d] + BN_EPS);
      ld += a.lg2[d] - 0.5f * logf(a.v2[d] + BN_EPS);
    }
    a.out_lp[b] = red[0] - 2048.f * ld;
  }
}

// ---------------------------------------------------------------- launch
extern "C" void kernel_launch(void* const* d_in, const int* in_sizes, int n_in,
                              void* d_out, int out_size, void* d_ws, size_t ws_size,
                              hipStream_t stream) {
  const float* x        = (const float*)d_in[0];
  const float* c        = (const float*)d_in[1];
  const float* bn1_mean = (const float*)d_in[2];
  const float* bn1_var  = (const float*)d_in[3];
  const float* bn1_lg   = (const float*)d_in[4];
  const float* bn1_beta = (const float*)d_in[5];
  const float* bn2_mean = (const float*)d_in[6];
  const float* bn2_var  = (const float*)d_in[7];
  const float* bn2_lg   = (const float*)d_in[8];
  const float* bn2_beta = (const float*)d_in[9];
  const float* sqrtT    = (const float*)d_in[10];
  const float* W0  = (const float*)d_in[11];
  const float* b0  = (const float*)d_in[12];
  const float* Wg0 = (const float*)d_in[13];
  const float* bg0 = (const float*)d_in[14];
  const float* Wb0 = (const float*)d_in[15];
  const float* W1  = (const float*)d_in[16];
  const float* b1  = (const float*)d_in[17];
  const float* Wg1 = (const float*)d_in[18];
  const float* bg1 = (const float*)d_in[19];
  const float* Wb1 = (const float*)d_in[20];
  const float* W2  = (const float*)d_in[21];
  const float* b2  = (const float*)d_in[22];
  const float* Wg2 = (const float*)d_in[23];
  const float* bg2 = (const float*)d_in[24];
  const float* Wb2 = (const float*)d_in[25];
  const float* W3  = (const float*)d_in[26];
  const float* b3  = (const float*)d_in[27];
  const float* Wg3 = (const float*)d_in[28];
  const float* bg3 = (const float*)d_in[29];
  const float* Wb3 = (const float*)d_in[30];

  char* base = (char*)d_ws;
  size_t off = 0;
  auto alloc = [&](size_t bytes) -> void* {
    void* pp = base + off;
    off += (bytes + 255) & ~(size_t)255;
    return pp;
  };
  u8* W1s = (u8*)alloc((size_t)512 * 512);
  u8* W2s = (u8*)alloc((size_t)512 * 512);
  u16* cb  = (u16*)alloc((size_t)PTS * 64 * 2);
  u16* Wpack = (u16*)alloc((size_t)6 * 512 * 64 * 2);
  float* bias_pack = (float*)alloc((size_t)3072 * 4);
  u16* GBi = (u16*)alloc((size_t)3 * PTS * 1024 * 2);
  const size_t SZi = (size_t)PTS * 1024;
  u16* GBi0 = GBi;
  u16* GBi1 = GBi + SZi;
  u16* GBi2 = GBi + 2 * SZi;
  float* G3f = (float*)alloc((size_t)PTS * 3 * 4);
  float* B3f = (float*)alloc((size_t)PTS * 3 * 4);
  float* E0 = (float*)alloc((size_t)512 * 8 * 4);
  float* E1 = (float*)alloc((size_t)512 * 4 * 4);
  float* E2 = (float*)alloc((size_t)512 * 8 * 4);
  float* accum6   = (float*)alloc((size_t)PTS * 6 * 4);
  float* x_cur    = (float*)alloc((size_t)PTS * 3 * 4);
  float* kx       = (float*)alloc((size_t)PTS * 3 * 4);
  float* kl       = (float*)alloc((size_t)PTS * 4);
  float* lp_state = (float*)alloc((size_t)PTS * 4);
  (void)ws_size; (void)in_sizes; (void)n_in; (void)out_size;

  PrepArgs pa{W1, W2, W1s, W2s, c, cb, Wg0, Wg1, Wg2, Wb0, Wb1, Wb2,
              bg0, bg1, bg2, Wpack, bias_pack, x, bn1_mean, bn1_var,
              bn1_lg, bn1_beta, x_cur, lp_state, Wg3, bg3, Wb3, G3f, B3f,
              W0, b0, b1, b2, W3, E0, E1, E2};
  prep_kernel<<<2048, 256, 0, stream>>>(pa);

  GatesGemmArgs gg{cb, Wpack, bias_pack, GBi};
  gates_gemm<<<dim3(64, 24), 256, 0, stream>>>(gg);

  auto ts_of = [](int s) -> float {
    static const float frac[4] = {0.f, 0.5f, 0.5f, 1.f};
    return (float)(s >> 2) + frac[s & 3];
  };

  for (int s = 0; s < 12; ++s) {
    StageArgs sa{sqrtT, (s == 0) ? 0.f : ts_of(s - 1), ts_of(s),
                 (s == 0) ? -1 : ((s - 1) & 3), accum6,
                 G3f, B3f, Wg3, Wb3, b3, x_cur, kx, kl, lp_state,
                 GBi0, GBi1, GBi2, E0, E1, E2, W1s, W2s};
    stage_kernel<<<PTS / 16, 512, 0, stream>>>(sa);
  }

  FinArgs fa{sqrtT, accum6, G3f, B3f, Wg3, Wb3, b3, x_cur, kx, kl,
             lp_state, bn2_mean, bn2_var, bn2_lg, bn2_beta,
             bn1_var, bn1_lg, (float*)d_out, (float*)d_out + PTS * 3};
  finalize_kernel<<<4, 256, 0, stream>>>(fa);
}